// Round 9
// baseline (196.410 us; speedup 1.0000x reference)
//
#include <hip/hip_runtime.h>

// Problem constants (fixed by setup_inputs):
//   a_arc, s_arc : [64, 1024, 1024] f32
//   adds, pos    : [64, 1024] int32 in [0, 50)
constexpr int NPOS  = 50;
constexpr int NBINS = NPOS * NPOS;   // 2500
constexpr int SL    = 1024;
constexpr int BZ    = 64;
constexpr float ALPHA = 0.3f;

using f32x4  = __attribute__((ext_vector_type(4))) float;
using bf16x8 = __attribute__((ext_vector_type(8))) short;

// ---------------- hist (MFMA) config — identical to R7 ----------------
constexpr int H_THREADS = 256;                    // 4 waves, 16 rows each
constexpr int H_ROWS    = 64;                     // rows per block
constexpr int KSPLIT    = 2;                      // j-halves (K=512/block)
constexpr int KSTEPS    = (SL / KSPLIT) / 32;     // 16 K-steps of 32
constexpr int H_BLOCKS  = BZ * (SL / H_ROWS) * KSPLIT;  // 2048
constexpr int PSTRIDE   = 2560;                   // partial-slice stride (floats)

// ---------------- reduce config ----------------
constexpr int R_THREADS = 256;                    // 4 waves x 64 bins
constexpr int R_BINGRP  = 40;                     // ceil(2500/64)
constexpr int R_PGRP    = 16;                     // 2048/128 slices per group
constexpr int R_BLOCKS  = R_BINGRP * R_PGRP;      // 640

// ---------------- apply kernel config ----------------
constexpr int A_THREADS      = 256;
constexpr int ROWS_PER_BLOCK = 32;
constexpr int BLOCKS_PER_B   = SL / ROWS_PER_BLOCK;   // 32
constexpr int A_BLOCKS       = BZ * BLOCKS_PER_B;     // 2048

// ---------------------------------------------------------------------------
// Kernel 1: score[p,q] partials via MFMA (R7-verified math). ONLY change vs
// R7: the flush is plain coalesced stores to a per-block slice g_part[blk]
// instead of global atomics — R0..R7 all hit a ~100-343us wall from
// same-line atomic serialization (~15ns x atomics-per-line), not from the
// main loop.
// ---------------------------------------------------------------------------
__global__ __launch_bounds__(H_THREADS) void hist_mfma(
    const float* __restrict__ a, const int* __restrict__ adds,
    float* __restrict__ g_part) {
  __shared__ int   adds_s[SL];           // 4 KB
  __shared__ float T_lds[H_ROWS][66];    // 16.9 KB (pad 64->66: bank-safe)
  __shared__ float acc2[NPOS * 52];      // 10.4 KB partial S
  __shared__ int   orderR[H_ROWS];       // rows sorted by p
  __shared__ int   cntR[NPOS], offm[NPOS];

  const int tid   = threadIdx.x;
  const int b     = blockIdx.x >> 5;     // 32 blocks per batch
  const int rem   = blockIdx.x & 31;
  const int rblk  = rem >> 1;            // 0..15
  const int khalf = rem & 1;
  const int row0  = rblk * H_ROWS;
  const int j0b   = khalf * (SL / KSPLIT);

  // --- stage adds row; zero counters/partials ---
  ((int4*)adds_s)[tid] = ((const int4*)(adds + (size_t)b * SL))[tid];
  for (int k = tid; k < NPOS * 52; k += H_THREADS) acc2[k] = 0.0f;
  if (tid < NPOS) cntR[tid] = 0;
  __syncthreads();

  // --- counting sort of the block's 64 rows by p = adds[row] ---
  if (tid < H_ROWS) atomicAdd(&cntR[adds_s[row0 + tid]], 1);
  __syncthreads();
  if (tid == 0) {
    int run = 0;
    for (int c = 0; c < NPOS; ++c) { offm[c] = run; run += cntR[c]; }
  }
  __syncthreads();
  if (tid < H_ROWS)
    orderR[atomicAdd(&offm[adds_s[row0 + tid]], 1)] = tid;
  // (orderR consumed only after the post-stage1 __syncthreads)

  // --- stage 1: T[r,q] = sum_j A[r,j] * (adds[j]==q), q in [0,64) ---
  const int wid = tid >> 6, lane = tid & 63;
  const int kg = lane >> 4, l15 = lane & 15;
  const float* __restrict__ Arow =
      a + ((size_t)b * SL + row0 + wid * 16 + l15) * SL + j0b + kg * 8;

  struct PF { float4 va, vb; int4 w0, w1; };
  auto loadpf = [&](PF& buf, int ks) {
    const float* p_ = Arow + ks * 32;
    buf.va = ((const float4*)p_)[0];
    buf.vb = ((const float4*)p_)[1];
    const int kkl = j0b + ks * 32 + kg * 8;
    buf.w0 = *(const int4*)&adds_s[kkl];
    buf.w1 = *(const int4*)&adds_s[kkl + 4];
  };

  f32x4 acc[4] = {};   // one per q-tile
  auto compute = [&](const PF& buf) {
    const float f[8] = {buf.va.x, buf.va.y, buf.va.z, buf.va.w,
                        buf.vb.x, buf.vb.y, buf.vb.z, buf.vb.w};
    const int av[8] = {buf.w0.x, buf.w0.y, buf.w0.z, buf.w0.w,
                       buf.w1.x, buf.w1.y, buf.w1.z, buf.w1.w};
    bf16x8 ah, al;
    #pragma unroll
    for (int e = 0; e < 8; ++e) {
      const unsigned u = __builtin_bit_cast(unsigned, f[e]);
      ah[e] = (short)(u >> 16);
      const float hf = __builtin_bit_cast(float, u & 0xFFFF0000u);
      const float lo = f[e] - hf;                  // exact residue
      al[e] = (short)(__builtin_bit_cast(unsigned, lo) >> 16);
    }
    #pragma unroll
    for (int qt = 0; qt < 4; ++qt) {
      const int q = qt * 16 + l15;
      bf16x8 bq;
      #pragma unroll
      for (int e = 0; e < 8; ++e)
        bq[e] = (av[e] == q) ? (short)0x3F80 : (short)0;
      acc[qt] = __builtin_amdgcn_mfma_f32_16x16x32_bf16(ah, bq, acc[qt], 0, 0, 0);
      acc[qt] = __builtin_amdgcn_mfma_f32_16x16x32_bf16(al, bq, acc[qt], 0, 0, 0);
    }
  };

  PF pfA, pfB;                       // named ping-pong: static indexing
  loadpf(pfA, 0);
  for (int ks = 0; ks < KSTEPS; ks += 2) {
    loadpf(pfB, ks + 1);             // in flight during compute(pfA)
    compute(pfA);
    if (ks + 2 < KSTEPS) loadpf(pfA, ks + 2);
    compute(pfB);
  }

  // C/D layout (m89/R6-verified): col = lane&15, row = (lane>>4)*4 + reg
  #pragma unroll
  for (int qt = 0; qt < 4; ++qt)
    #pragma unroll
    for (int r = 0; r < 4; ++r)
      T_lds[wid * 16 + kg * 4 + r][qt * 16 + l15] = acc[qt][r];
  __syncthreads();

  // --- stage 2: S[p,q] += sum_{rows with p} T[row,q], via sorted runs ---
  {
    const int q = tid & 63, quarter = tid >> 6;   // wave == quarter
    float s = 0.0f;
    int pcur = -1;
    for (int k2 = 0; k2 < H_ROWS / 4; ++k2) {
      const int row = orderR[quarter * (H_ROWS / 4) + k2];  // wave-uniform
      const int p   = adds_s[row0 + row];                   // wave-uniform
      if (p != pcur) {                                      // uniform branch
        if (pcur >= 0 && q < NPOS) atomicAdd(&acc2[pcur * 52 + q], s);
        pcur = p; s = 0.0f;
      }
      s += T_lds[row][q];                                   // conflict-free
    }
    if (pcur >= 0 && q < NPOS) atomicAdd(&acc2[pcur * 52 + q], s);
  }
  __syncthreads();

  // --- flush: PLAIN coalesced stores to this block's private slice ---
  float* __restrict__ gp = g_part + (size_t)blockIdx.x * PSTRIDE;
  for (int bin = tid; bin < NBINS; bin += H_THREADS)
    gp[bin] = acc2[(bin / NPOS) * 52 + (bin % NPOS)];
}

// ---------------------------------------------------------------------------
// Kernel 1.5: g_hist[bin] = sum over 2048 slices of g_part[slice][bin].
// 640 blocks; each handles 64 bins x 128 slices; 16 low-contention atomics
// per bin close the sum.
// ---------------------------------------------------------------------------
__global__ __launch_bounds__(R_THREADS) void reduce_kernel(
    const float* __restrict__ g_part, float* __restrict__ g_hist) {
  __shared__ float red[4][64];
  const int bx  = blockIdx.x % R_BINGRP;
  const int py  = blockIdx.x / R_BINGRP;
  const int w   = threadIdx.x >> 6, l = threadIdx.x & 63;
  const int bin = bx * 64 + l;

  float s = 0.0f;
  if (bin < NBINS) {
    const float* base = g_part + ((size_t)py * 128 + w * 32) * PSTRIDE + bin;
    #pragma unroll
    for (int r = 0; r < 32; ++r) s += base[(size_t)r * PSTRIDE];
  }
  red[w][l] = s;
  __syncthreads();
  if (w == 0 && bin < NBINS)
    atomicAdd(&g_hist[bin], red[0][l] + red[1][l] + red[2][l] + red[3][l]);
}

// ---------------------------------------------------------------------------
// Kernel 2: out = s_arc + ALPHA * sigmoid(g_hist)[pos-pair bin]
// Measured ~6.1 TB/s (HBM roofline) — unchanged.
// ---------------------------------------------------------------------------
__global__ __launch_bounds__(A_THREADS) void apply_kernel(
    const float* __restrict__ s, const int* __restrict__ pos,
    const float* __restrict__ g_hist, float* __restrict__ out) {
  __shared__ float sig[NBINS];
  __shared__ int   pos_s[SL];

  const int tid = threadIdx.x;
  const int b   = blockIdx.x / BLOCKS_PER_B;
  const int i0  = (blockIdx.x % BLOCKS_PER_B) * ROWS_PER_BLOCK;

  ((int4*)pos_s)[tid] = ((const int4*)(pos + (size_t)b * SL))[tid];
  for (int k = tid; k < NBINS; k += A_THREADS) {
    const float h = g_hist[k];
    sig[k] = 1.0f / (1.0f + __expf(-h));
  }
  __syncthreads();

  const int4 pj = ((const int4*)pos_s)[tid];
  const size_t rowoff = ((size_t)b * SL + i0) * SL;
  const float4* __restrict__ srow = (const float4*)(s + rowoff);
  float4* __restrict__ orow = (float4*)(out + rowoff);

  for (int r = 0; r < ROWS_PER_BLOCK; ++r) {
    const int base = pos_s[i0 + r] * NPOS;    // wave-uniform broadcast
    const float4 sv = srow[(size_t)r * (SL / 4) + tid];
    float4 ov;
    ov.x = sv.x + ALPHA * sig[base + pj.x];
    ov.y = sv.y + ALPHA * sig[base + pj.y];
    ov.z = sv.z + ALPHA * sig[base + pj.z];
    ov.w = sv.w + ALPHA * sig[base + pj.w];
    orow[(size_t)r * (SL / 4) + tid] = ov;
  }
}

extern "C" void kernel_launch(void* const* d_in, const int* in_sizes, int n_in,
                              void* d_out, int out_size, void* d_ws, size_t ws_size,
                              hipStream_t stream) {
  const float* a_arc = (const float*)d_in[0];
  const float* s_arc = (const float*)d_in[1];
  const int*   adds  = (const int*)d_in[2];
  const int*   pos   = (const int*)d_in[3];
  float* out    = (float*)d_out;
  float* g_hist = (float*)d_ws;          // 2500 floats
  float* g_part = g_hist + 4096;         // 2048 x 2560 floats = 20.97 MB

  // g_hist is atomically accumulated by reduce_kernel -> zero it each call.
  // g_part needs NO init: every slot is overwritten by hist_mfma each call.
  hipMemsetAsync(g_hist, 0, NBINS * sizeof(float), stream);

  hist_mfma    <<<H_BLOCKS, H_THREADS, 0, stream>>>(a_arc, adds, g_part);
  reduce_kernel<<<R_BLOCKS, R_THREADS, 0, stream>>>(g_part, g_hist);
  apply_kernel <<<A_BLOCKS, A_THREADS, 0, stream>>>(s_arc, pos, g_hist, out);
}